// Round 1
// baseline (186.391 us; speedup 1.0000x reference)
//
#include <hip/hip_runtime.h>

// Problem constants (match reference)
#define BB 128
#define SS 8192
#define VV 128000

// Output element offsets (flat float32 view of d_out, tuple return order)
#define OFF_TOK 0
#define OFF_LTI (OFF_TOK + BB)
#define OFF_MASK (OFF_LTI + BB)
#define OFF_GEN (OFF_MASK + BB * SS)
#define OFF_STR (OFF_GEN + BB * SS)
#define OFF_GI (OFF_STR + BB * SS)
#define OFF_CNT (OFF_GI + BB)

// Kernel A: attention_mask / generated_tokens / generated_tokens_streaming copies
// with scatter fixups, plus the three tiny (B,) outputs.
// grid = (S/(256*4), B), block = 256. 4 elements per thread, 16B vector ops.
__global__ void __launch_bounds__(256)
k_mid(const int* __restrict__ tokens,
      const int* __restrict__ lti_in,
      const float* __restrict__ mask_in,
      const int* __restrict__ gen_in,
      const int* __restrict__ str_in,
      const int* __restrict__ gi_in,
      float* __restrict__ out)
{
    const int b  = blockIdx.y;
    const int s0 = (blockIdx.x * blockDim.x + threadIdx.x) * 4;

    // wave-uniform per-batch scalars (b is blockIdx-uniform -> scalar loads)
    const int tok     = tokens[b];
    const int lti_new = min(lti_in[b] + 1, SS - 1);
    const int gi_old  = gi_in[b];   // scatter position uses PRE-increment index

    const size_t row = (size_t)b * SS + s0;

    // attention_mask: copy, set 1.0 at s == lti_new
    float4 m = *(const float4*)(mask_in + row);
    if (lti_new >= s0 && lti_new < s0 + 4)
        ((float*)&m)[lti_new - s0] = 1.0f;
    *(float4*)(out + OFF_MASK + row) = m;

    // generated_tokens: copy int->float, set tok at s == gi_old
    int4 g = *(const int4*)(gen_in + row);
    float4 go = make_float4((float)g.x, (float)g.y, (float)g.z, (float)g.w);
    if (gi_old >= s0 && gi_old < s0 + 4)
        ((float*)&go)[gi_old - s0] = (float)tok;
    *(float4*)(out + OFF_GEN + row) = go;

    // generated_tokens_streaming: same
    int4 h = *(const int4*)(str_in + row);
    float4 ho = make_float4((float)h.x, (float)h.y, (float)h.z, (float)h.w);
    if (gi_old >= s0 && gi_old < s0 + 4)
        ((float*)&ho)[gi_old - s0] = (float)tok;
    *(float4*)(out + OFF_STR + row) = ho;

    // tiny outputs: tokens, lti_new, gi_new — one block does them
    if (blockIdx.x == 0 && blockIdx.y == 0 && threadIdx.x < BB) {
        const int i = threadIdx.x;
        out[OFF_TOK + i] = (float)tokens[i];
        out[OFF_LTI + i] = (float)min(lti_in[i] + 1, SS - 1);
        out[OFF_GI  + i] = (float)min(gi_in[i] + 1, SS - 1);
    }
}

// Kernel B: token_count copy int->float with per-row histogram increment.
// grid = (V/(256*4), B), block = 256. No atomics: exactly one +1 per row.
__global__ void __launch_bounds__(256)
k_cnt(const int* __restrict__ tokens,
      const int* __restrict__ cnt_in,
      float* __restrict__ out)
{
    const int b  = blockIdx.y;
    const int v0 = (blockIdx.x * blockDim.x + threadIdx.x) * 4;
    const int tok = tokens[b];   // wave-uniform scalar load

    const size_t row = (size_t)b * VV + v0;
    int4 c = *(const int4*)(cnt_in + row);
    float4 co = make_float4((float)c.x, (float)c.y, (float)c.z, (float)c.w);
    if (tok >= v0 && tok < v0 + 4)
        ((float*)&co)[tok - v0] += 1.0f;
    *(float4*)(out + OFF_CNT + row) = co;
}

extern "C" void kernel_launch(void* const* d_in, const int* in_sizes, int n_in,
                              void* d_out, int out_size, void* d_ws, size_t ws_size,
                              hipStream_t stream) {
    const int*   tokens = (const int*)  d_in[0];
    const int*   lti    = (const int*)  d_in[1];
    const float* mask   = (const float*)d_in[2];
    const int*   gen    = (const int*)  d_in[3];
    const int*   strm   = (const int*)  d_in[4];
    const int*   gi     = (const int*)  d_in[5];
    const int*   cnt    = (const int*)  d_in[6];
    float* out = (float*)d_out;

    dim3 gA(SS / (256 * 4), BB);   // (8, 128)
    k_mid<<<gA, dim3(256), 0, stream>>>(tokens, lti, mask, gen, strm, gi, out);

    dim3 gB(VV / (256 * 4), BB);   // (125, 128)
    k_cnt<<<gB, dim3(256), 0, stream>>>(tokens, cnt, out);
}

// Round 3
// 144.465 us; speedup vs baseline: 1.2902x; 1.2902x over previous
//
#include <hip/hip_runtime.h>

// Problem constants (match reference)
#define BB 128
#define SS 8192
#define VV 128000

// Output element offsets (flat float32 view of d_out, tuple return order)
#define OFF_TOK 0
#define OFF_LTI (OFF_TOK + BB)
#define OFF_MASK (OFF_LTI + BB)            // 256
#define OFF_GEN (OFF_MASK + BB * SS)       // 1048832
#define OFF_STR (OFF_GEN + BB * SS)        // 2097408
#define OFF_GI  (OFF_STR + BB * SS)        // 3145984
#define OFF_CNT (OFF_GI + BB)              // 3146112

// Native clang vectors — required by __builtin_nontemporal_{load,store}
typedef float f32x4 __attribute__((ext_vector_type(4)));
typedef int   i32x4 __attribute__((ext_vector_type(4)));

// One block processes 4096 elements = 1024 float4 chunks (256 thr x 4 chunks).
#define NB_S   256     // blocks per S-region: 128*8192/4096
#define NB_CNT 4000    // blocks for count region: 128*128000/4096
#define NB_TOTAL (3 * NB_S + NB_CNT + 1)   // 4769

__global__ void __launch_bounds__(256)
k_fused(const int* __restrict__ tokens,
        const int* __restrict__ lti_in,
        const float* __restrict__ mask_in,
        const int* __restrict__ gen_in,
        const int* __restrict__ str_in,
        const int* __restrict__ gi_in,
        const int* __restrict__ cnt_in,
        float* __restrict__ out)
{
    const int bid = blockIdx.x;
    const int tid = threadIdx.x;

    if (bid < 3 * NB_S) {
        // ---- attention_mask / generated_tokens / generated_tokens_streaming ----
        const int region = bid >> 8;       // 0=mask, 1=gen, 2=str (block-uniform)
        const int rbid   = bid & 255;
        #pragma unroll
        for (int j = 0; j < 4; ++j) {
            const int    c  = rbid * 1024 + j * 256 + tid;  // float4 chunk in region
            const int    b  = c >> 11;                      // 2048 chunks per S-row
            const int    s0 = (c & 2047) << 2;              // first s covered by chunk
            const size_t e  = (size_t)c << 2;               // flat element offset

            if (region == 0) {
                f32x4 m = __builtin_nontemporal_load((const f32x4*)(mask_in + e));
                const int lti_new = min(lti_in[b] + 1, SS - 1);
                if ((unsigned)(lti_new - s0) < 4u)
                    m[lti_new - s0] = 1.0f;
                __builtin_nontemporal_store(m, (f32x4*)(out + OFF_MASK + e));
            } else {
                const int* src = (region == 1) ? gen_in : str_in;
                const int  dst = (region == 1) ? OFF_GEN : OFF_STR;
                i32x4 g = __builtin_nontemporal_load((const i32x4*)(src + e));
                f32x4 go;
                go[0] = (float)g[0]; go[1] = (float)g[1];
                go[2] = (float)g[2]; go[3] = (float)g[3];
                const int gi_old = gi_in[b];                // scatter at PRE-increment idx
                if ((unsigned)(gi_old - s0) < 4u)
                    go[gi_old - s0] = (float)tokens[b];
                __builtin_nontemporal_store(go, (f32x4*)(out + dst + e));
            }
        }
    } else if (bid < 3 * NB_S + NB_CNT) {
        // ---- token_count: copy int->float, +1 at tokens[b] per row (no atomics) ----
        const int rbid = bid - 3 * NB_S;
        #pragma unroll
        for (int j = 0; j < 4; ++j) {
            const int    c  = rbid * 1024 + j * 256 + tid;
            const int    b  = c / 32000;                    // 32000 chunks per V-row
            const int    v0 = (c - b * 32000) << 2;
            const size_t e  = (size_t)c << 2;

            i32x4 cc = __builtin_nontemporal_load((const i32x4*)(cnt_in + e));
            f32x4 co;
            co[0] = (float)cc[0]; co[1] = (float)cc[1];
            co[2] = (float)cc[2]; co[3] = (float)cc[3];
            const int tok = tokens[b];
            if ((unsigned)(tok - v0) < 4u)
                co[tok - v0] += 1.0f;
            __builtin_nontemporal_store(co, (f32x4*)(out + OFF_CNT + e));
        }
    } else {
        // ---- tiny (B,) outputs: tokens, lti+1 clamped, gi+1 clamped ----
        if (tid < BB) {
            out[OFF_TOK + tid] = (float)tokens[tid];
            out[OFF_LTI + tid] = (float)min(lti_in[tid] + 1, SS - 1);
            out[OFF_GI  + tid] = (float)min(gi_in[tid] + 1, SS - 1);
        }
    }
}

extern "C" void kernel_launch(void* const* d_in, const int* in_sizes, int n_in,
                              void* d_out, int out_size, void* d_ws, size_t ws_size,
                              hipStream_t stream) {
    const int*   tokens = (const int*)  d_in[0];
    const int*   lti    = (const int*)  d_in[1];
    const float* mask   = (const float*)d_in[2];
    const int*   gen    = (const int*)  d_in[3];
    const int*   strm   = (const int*)  d_in[4];
    const int*   gi     = (const int*)  d_in[5];
    const int*   cnt    = (const int*)  d_in[6];
    float* out = (float*)d_out;

    k_fused<<<dim3(NB_TOTAL), dim3(256), 0, stream>>>(
        tokens, lti, mask, gen, strm, gi, cnt, out);
}